// Round 1
// 1779.932 us; speedup vs baseline: 1.1442x; 1.1442x over previous
//
#include <hip/hip_runtime.h>
#include <stdint.h>
#include <stddef.h>

// BitLinear: out[i,j] = (gamma_i * alpha / 127) * sum_k q[i,k] * t[j,k]
//   q = rint(x / gamma * 127)  in [-127,127]  (exact in bf16)
//   t = clip(rint(w / alpha), -1, 1)          (exact in bf16)
// Integer dot products are exact in bf16 MFMA with fp32 accum (< 2^24).

#define FAN_IN  4096
#define FAN_OUT 16384
#define NROWS   8192                       // BATCH*SEQ = 4*2048
#define NW_ELEM (FAN_OUT * FAN_IN)         // 67108864

typedef __bf16 bf16_t;
typedef __bf16 bf16x4 __attribute__((ext_vector_type(4)));
typedef __bf16 bf16x8 __attribute__((ext_vector_type(8)));
typedef float  f32x4  __attribute__((ext_vector_type(4)));

// ---------------- K1: sum of |w| (fp64) ----------------
__global__ __launch_bounds__(256) void k_abs_sum(const float* __restrict__ w,
                                                 double* __restrict__ sum) {
  const float4* w4 = (const float4*)w;
  const int n4 = NW_ELEM / 4;
  int tid = blockIdx.x * 256 + threadIdx.x;
  int stride = gridDim.x * 256;
  double s = 0.0;
  for (int i = tid; i < n4; i += stride) {
    float4 v = w4[i];
    s += (double)fabsf(v.x);
    s += (double)fabsf(v.y);
    s += (double)fabsf(v.z);
    s += (double)fabsf(v.w);
  }
  __shared__ double sd[256];
  sd[threadIdx.x] = s;
  __syncthreads();
  for (int off = 128; off > 0; off >>= 1) {
    if (threadIdx.x < off) sd[threadIdx.x] += sd[threadIdx.x + off];
    __syncthreads();
  }
  if (threadIdx.x == 0) atomicAdd(sum, sd[0]);
}

// ---------------- K2: ternarize weights -> bf16 ----------------
__global__ __launch_bounds__(256) void k_quant_w(const float* __restrict__ w,
                                                 bf16_t* __restrict__ t,
                                                 const double* __restrict__ sum) {
  // fp32 division to match numpy's boundary rounding; rintf = round-half-even
  const float alpha = (float)(*sum / (double)NW_ELEM + 1e-8);
  const float4* w4 = (const float4*)w;
  bf16x4* t4 = (bf16x4*)t;
  const int n4 = NW_ELEM / 4;
  int tid = blockIdx.x * 256 + threadIdx.x;
  int stride = gridDim.x * 256;
  for (int i = tid; i < n4; i += stride) {
    float4 v = w4[i];
    float a0 = fminf(fmaxf(rintf(v.x / alpha), -1.0f), 1.0f);
    float a1 = fminf(fmaxf(rintf(v.y / alpha), -1.0f), 1.0f);
    float a2 = fminf(fmaxf(rintf(v.z / alpha), -1.0f), 1.0f);
    float a3 = fminf(fmaxf(rintf(v.w / alpha), -1.0f), 1.0f);
    bf16x4 o = { (bf16_t)a0, (bf16_t)a1, (bf16_t)a2, (bf16_t)a3 };
    t4[i] = o;
  }
}

// ---------------- K3: per-row absmax + int8-code quant of x -> bf16 ----------------
__global__ __launch_bounds__(256) void k_quant_x(const float* __restrict__ x,
                                                 bf16_t* __restrict__ q,
                                                 float* __restrict__ gamma) {
  const int row = blockIdx.x;
  const float4* xr = (const float4*)(x + (size_t)row * FAN_IN);
  float4 v[4];
  float m = 0.0f;
#pragma unroll
  for (int i = 0; i < 4; ++i) {
    v[i] = xr[threadIdx.x + i * 256];
    m = fmaxf(m, fmaxf(fmaxf(fabsf(v[i].x), fabsf(v[i].y)),
                       fmaxf(fabsf(v[i].z), fabsf(v[i].w))));
  }
#pragma unroll
  for (int off = 32; off > 0; off >>= 1) m = fmaxf(m, __shfl_down(m, off));
  __shared__ float sm[4];
  if ((threadIdx.x & 63) == 0) sm[threadIdx.x >> 6] = m;
  __syncthreads();
  float g = fmaxf(fmaxf(sm[0], sm[1]), fmaxf(sm[2], sm[3]));
  g = fmaxf(g, 1e-8f);
  const float sc = 127.0f / g;
  bf16x4* qr = (bf16x4*)(q + (size_t)row * FAN_IN);
#pragma unroll
  for (int i = 0; i < 4; ++i) {
    bf16x4 o = { (bf16_t)rintf(v[i].x * sc), (bf16_t)rintf(v[i].y * sc),
                 (bf16_t)rintf(v[i].z * sc), (bf16_t)rintf(v[i].w * sc) };
    qr[threadIdx.x + i * 256] = o;
  }
  if (threadIdx.x == 0) gamma[row] = g;
}

// ---------------- K4: GEMM, 256x256 tile, 8-phase counted-vmcnt schedule --------
// m201 structure in plain HIP: BM=BN=256, BK=64, 512 thr = 8 waves (2Mx4N),
// per-wave 128x64 output, mfma_f32_16x16x32_bf16, global_load_lds width=16.
// LDS 128 KiB = 2 buffers x (A 256x64 + B 256x64) bf16.
// LDS layout: chunked 16B, source-side XOR swizzle (chunk cc of row m holds
// global chunk cc^(m&7)) -> ds_read_b128 column reads measured 0 bank conflicts.
// Schedule: 4 phases/K-tile, each {ds_read frag subtile | 2x global_load_lds
// prefetch -> s_barrier -> setprio(1) -> 16 MFMA -> setprio(0) -> s_barrier}.
// Counted vmcnt(2) ONLY at phase 3 (per K-tile); never a full drain in the
// steady-state loop.  Tile T's 8 load-issues occupy slots P(T-2,3),P(T-1,0..2),
// so vmcnt(2) at P(T-1,3) proves tile T landed with tile T+1's first 2 in flight.

#define BM 256
#define BN 256
#define BK 64
#define KTILES (FAN_IN / BK)   // 64

#define GLOAD(gp, lp) \
  __builtin_amdgcn_global_load_lds( \
      (const __attribute__((address_space(1))) uint32_t*)(gp), \
      (__attribute__((address_space(3))) uint32_t*)(lp), 16, 0, 0)

// raw barrier with compiler memory fence: no vmcnt drain, no mem-op motion across
#define BAR() asm volatile("s_barrier" ::: "memory")

__global__ __launch_bounds__(512, 2) void k_gemm(const bf16_t* __restrict__ Q,
                                                 const bf16_t* __restrict__ T,
                                                 const float* __restrict__ gamma,
                                                 const double* __restrict__ sum,
                                                 float* __restrict__ out) {
  __shared__ __align__(16) bf16_t As[2][BM * BK];
  __shared__ __align__(16) bf16_t Bs[2][BM * BK];

  // bijective XCD swizzle (2048 % 8 == 0): each XCD owns 8 contiguous jn
  // columns; im sweeps inside -> concurrent ~4x8 tile window per XCD L2.
  const int bid = blockIdx.x;
  const int loc = bid >> 3;                   // 0..255 (sequential per XCD)
  const int im  = loc >> 3;                   // 0..31
  const int jn  = (bid & 7) * 8 + (loc & 7);  // 0..63
  const size_t i0 = (size_t)im * BM;
  const size_t j0 = (size_t)jn * BN;

  const int tid  = threadIdx.x;
  const int lane = tid & 63;
  const int wave = tid >> 6;
  const int wm = wave >> 2;                   // 0..1 (M)
  const int wn = wave & 3;                    // 0..3 (N)
  const int ldsbase = (tid & ~63) * 8;        // wave-uniform; HW adds lane*16B

  f32x4 acc[8][4] = {};
  const bf16_t* gA[4];
  const bf16_t* gB[4];
  int aOff[4][2], bOff[4][2];

  // staging map: issue s covers chunks ci = s*512+tid; row m=ci>>3, slot cc=ci&7
  // holds global chunk cg = cc ^ (m&7)
#pragma unroll
  for (int s = 0; s < 4; ++s) {
    int ci = s * 512 + tid;
    int m  = ci >> 3;
    int cg = (ci & 7) ^ (m & 7);
    gA[s] = Q + (i0 + m) * FAN_IN + cg * 8;
    gB[s] = T + (j0 + m) * FAN_IN + cg * 8;
  }
  // fragment read offsets (elements): (m*8 + (crow ^ (m&7)))*8 ; mi 4..7 = +4096
#pragma unroll
  for (int f = 0; f < 4; ++f) {
#pragma unroll
    for (int kk = 0; kk < 2; ++kk) {
      const int crow = kk * 4 + (lane >> 4);
      const int ma = wm * 128 + f * 16 + (lane & 15);
      const int mb = wn * 64  + f * 16 + (lane & 15);
      aOff[f][kk] = ma * 64 + (crow ^ (ma & 7)) * 8;
      bOff[f][kk] = mb * 64 + (crow ^ (mb & 7)) * 8;
    }
  }

  bf16_t* As0 = &As[0][0]; bf16_t* As1 = &As[1][0];
  bf16_t* Bs0 = &Bs[0][0]; bf16_t* Bs1 = &Bs[1][0];

  // ---- prologue: tile0 fully (8 issues) into buf0, tile1 A-halves (2) into buf1
#pragma unroll
  for (int s = 0; s < 4; ++s) { GLOAD(gA[s], As0 + s * 4096 + ldsbase); gA[s] += BK; }
#pragma unroll
  for (int s = 0; s < 4; ++s) { GLOAD(gB[s], Bs0 + s * 4096 + ldsbase); gB[s] += BK; }
  GLOAD(gA[0], As1 + 0 * 4096 + ldsbase); gA[0] += BK;
  GLOAD(gA[1], As1 + 1 * 4096 + ldsbase); gA[1] += BK;
  asm volatile("s_waitcnt vmcnt(2)" ::: "memory");   // tile0's 8 landed
  BAR();

  // one K-tile = 4 phases; cA/cB = compute buffers, sA/sB = prefetch buffers
  auto tile = [&](int t, bf16_t* cA, bf16_t* cB, bf16_t* sA, bf16_t* sB) {
    bf16x8 aR[4][2], bR[4][2];
    const bool pf = (t < KTILES - 1);
    // ---------------- phase 0: LD A(lo) x8 + B(0-1) x4 | stage A2,A3(t+1) ----
#pragma unroll
    for (int mi = 0; mi < 4; ++mi)
#pragma unroll
      for (int kk = 0; kk < 2; ++kk)
        aR[mi][kk] = *(const bf16x8*)(cA + aOff[mi][kk]);
#pragma unroll
    for (int ni = 0; ni < 2; ++ni)
#pragma unroll
      for (int kk = 0; kk < 2; ++kk)
        bR[ni][kk] = *(const bf16x8*)(cB + bOff[ni][kk]);
    if (pf) {
      GLOAD(gA[2], sA + 2 * 4096 + ldsbase); gA[2] += BK;
      GLOAD(gA[3], sA + 3 * 4096 + ldsbase); gA[3] += BK;
    }
    BAR();
    __builtin_amdgcn_s_setprio(1);
#pragma unroll
    for (int kk = 0; kk < 2; ++kk)
#pragma unroll
      for (int mi = 0; mi < 4; ++mi)
#pragma unroll
        for (int ni = 0; ni < 2; ++ni)
          acc[mi][ni] = __builtin_amdgcn_mfma_f32_16x16x32_bf16(
              aR[mi][kk], bR[ni][kk], acc[mi][ni], 0, 0, 0);
    __builtin_amdgcn_s_setprio(0);
    BAR();
    // ---------------- phase 1: LD B(2-3) x4 | stage B0,B1(t+1) --------------
#pragma unroll
    for (int ni = 2; ni < 4; ++ni)
#pragma unroll
      for (int kk = 0; kk < 2; ++kk)
        bR[ni][kk] = *(const bf16x8*)(cB + bOff[ni][kk]);
    if (pf) {
      GLOAD(gB[0], sB + 0 * 4096 + ldsbase); gB[0] += BK;
      GLOAD(gB[1], sB + 1 * 4096 + ldsbase); gB[1] += BK;
    }
    BAR();
    __builtin_amdgcn_s_setprio(1);
#pragma unroll
    for (int kk = 0; kk < 2; ++kk)
#pragma unroll
      for (int mi = 0; mi < 4; ++mi)
#pragma unroll
        for (int ni = 2; ni < 4; ++ni)
          acc[mi][ni] = __builtin_amdgcn_mfma_f32_16x16x32_bf16(
              aR[mi][kk], bR[ni][kk], acc[mi][ni], 0, 0, 0);
    __builtin_amdgcn_s_setprio(0);
    BAR();
    // ---------------- phase 2: LD A(hi) x8 | stage B2,B3(t+1) ---------------
    // (bR[0..1] still live from phase 0)
#pragma unroll
    for (int mi = 0; mi < 4; ++mi)
#pragma unroll
      for (int kk = 0; kk < 2; ++kk)
        aR[mi][kk] = *(const bf16x8*)(cA + 4096 + aOff[mi][kk]);
    if (pf) {
      GLOAD(gB[2], sB + 2 * 4096 + ldsbase); gB[2] += BK;
      GLOAD(gB[3], sB + 3 * 4096 + ldsbase); gB[3] += BK;
    }
    BAR();
    __builtin_amdgcn_s_setprio(1);
#pragma unroll
    for (int kk = 0; kk < 2; ++kk)
#pragma unroll
      for (int mi = 0; mi < 4; ++mi)
#pragma unroll
        for (int ni = 0; ni < 2; ++ni)
          acc[4 + mi][ni] = __builtin_amdgcn_mfma_f32_16x16x32_bf16(
              aR[mi][kk], bR[ni][kk], acc[4 + mi][ni], 0, 0, 0);
    __builtin_amdgcn_s_setprio(0);
    BAR();
    // ---------------- phase 3: stage A0,A1(t+2) into cA buf | counted vmcnt -
    // cA buffer is free: all waves' reads of it finished before phase-2's
    // closing barrier.  vmcnt(2) = tile t+1's 8 loads done, its own 2 in flight.
    if (t < KTILES - 2) {
      GLOAD(gA[0], cA + 0 * 4096 + ldsbase); gA[0] += BK;
      GLOAD(gA[1], cA + 1 * 4096 + ldsbase); gA[1] += BK;
      asm volatile("s_waitcnt vmcnt(2)" ::: "memory");
    } else if (t == KTILES - 2) {
      asm volatile("s_waitcnt vmcnt(0)" ::: "memory");
    }
    BAR();
    __builtin_amdgcn_s_setprio(1);
#pragma unroll
    for (int kk = 0; kk < 2; ++kk)
#pragma unroll
      for (int mi = 0; mi < 4; ++mi)
#pragma unroll
        for (int ni = 2; ni < 4; ++ni)
          acc[4 + mi][ni] = __builtin_amdgcn_mfma_f32_16x16x32_bf16(
              aR[mi][kk], bR[ni][kk], acc[4 + mi][ni], 0, 0, 0);
    __builtin_amdgcn_s_setprio(0);
    BAR();
  };

  for (int tt = 0; tt < KTILES; tt += 2) {
    tile(tt,     As0, Bs0, As1, Bs1);
    tile(tt + 1, As1, Bs1, As0, Bs0);
  }

  // epilogue: C/D layout col=lane&15, row=(lane>>4)*4+r  (verified m89/m91)
  const float alpha = (float)(*sum / (double)NW_ELEM + 1e-8);
  const int lr = lane >> 4;
  const int lc = lane & 15;
#pragma unroll
  for (int mi = 0; mi < 8; ++mi) {
    size_t gi = i0 + wm * 128 + mi * 16 + lr * 4;
#pragma unroll
    for (int r = 0; r < 4; ++r) {
      const float scl = gamma[gi + r] * alpha * (1.0f / 127.0f);
      float* orow = out + (gi + r) * (size_t)FAN_OUT;
#pragma unroll
      for (int ni = 0; ni < 4; ++ni) {
        size_t gj = j0 + wn * 64 + ni * 16 + lc;
        orow[gj] = acc[mi][ni][r] * scl;
      }
    }
  }
}

// ---------------- launch ----------------
extern "C" void kernel_launch(void* const* d_in, const int* in_sizes, int n_in,
                              void* d_out, int out_size, void* d_ws, size_t ws_size,
                              hipStream_t stream) {
  const float* x = (const float*)d_in[0];
  const float* w = (const float*)d_in[1];
  float* out = (float*)d_out;
  char* ws = (char*)d_ws;

  // ws layout: [0,8) fp64 sum | [1024, 33792) gamma (8192 f32)
  //            [1 MiB, +64 MiB) q bf16 | then t bf16 (128 MiB). Total ~193 MiB.
  double* sum = (double*)ws;
  float* gamma = (float*)(ws + 1024);
  bf16_t* q = (bf16_t*)(ws + (1u << 20));
  bf16_t* t = (bf16_t*)(ws + (size_t)(1u << 20) + (size_t)NROWS * FAN_IN * 2);

  hipMemsetAsync(sum, 0, sizeof(double), stream);
  k_abs_sum<<<1024, 256, 0, stream>>>(w, sum);
  k_quant_w<<<4096, 256, 0, stream>>>(w, t, sum);
  k_quant_x<<<NROWS, 256, 0, stream>>>(x, q, gamma);
  k_gemm<<<(NROWS / BM) * (FAN_OUT / BN), 512, 0, stream>>>(q, t, gamma, sum, out);
}

// Round 2
// 1264.175 us; speedup vs baseline: 1.6110x; 1.4080x over previous
//
#include <hip/hip_runtime.h>
#include <stdint.h>
#include <stddef.h>

// BitLinear: out[i,j] = (gamma_i * alpha / 127) * sum_k q[i,k] * t[j,k]
//   q = rint(x / gamma * 127)  in [-127,127]  -> int8 (exact)
//   t = clip(rint(w / alpha), -1, 1)          -> int8 (exact)
// Integer dot products are exact in i8 MFMA with i32 accum (|acc| < 2^24),
// and i32->f32 in the epilogue is exact. Output bits identical to the bf16
// path and to a fp64 reference of the quantized math.

#define FAN_IN  4096
#define FAN_OUT 16384
#define NROWS   8192                       // BATCH*SEQ = 4*2048
#define NW_ELEM (FAN_OUT * FAN_IN)         // 67108864

typedef __bf16 bf16_t;
typedef int   i32x4 __attribute__((ext_vector_type(4)));

// ---------------- K1: sum of |w| (fp64) ----------------
__global__ __launch_bounds__(256) void k_abs_sum(const float* __restrict__ w,
                                                 double* __restrict__ sum) {
  const float4* w4 = (const float4*)w;
  const int n4 = NW_ELEM / 4;
  int tid = blockIdx.x * 256 + threadIdx.x;
  int stride = gridDim.x * 256;
  double s = 0.0;
  for (int i = tid; i < n4; i += stride) {
    float4 v = w4[i];
    s += (double)fabsf(v.x);
    s += (double)fabsf(v.y);
    s += (double)fabsf(v.z);
    s += (double)fabsf(v.w);
  }
  __shared__ double sd[256];
  sd[threadIdx.x] = s;
  __syncthreads();
  for (int off = 128; off > 0; off >>= 1) {
    if (threadIdx.x < off) sd[threadIdx.x] += sd[threadIdx.x + off];
    __syncthreads();
  }
  if (threadIdx.x == 0) atomicAdd(sum, sd[0]);
}

// ---------------- K2: ternarize weights -> int8 ----------------
__global__ __launch_bounds__(256) void k_quant_w(const float* __restrict__ w,
                                                 int8_t* __restrict__ t,
                                                 const double* __restrict__ sum) {
  // fp32 division to match numpy's boundary rounding; rintf = round-half-even
  const float alpha = (float)(*sum / (double)NW_ELEM + 1e-8);
  const float4* w4 = (const float4*)w;
  int* t4 = (int*)t;                       // 4 x i8 packed per float4
  const int n4 = NW_ELEM / 4;
  int tid = blockIdx.x * 256 + threadIdx.x;
  int stride = gridDim.x * 256;
  for (int i = tid; i < n4; i += stride) {
    float4 v = w4[i];
    int a0 = (int)fminf(fmaxf(rintf(v.x / alpha), -1.0f), 1.0f);
    int a1 = (int)fminf(fmaxf(rintf(v.y / alpha), -1.0f), 1.0f);
    int a2 = (int)fminf(fmaxf(rintf(v.z / alpha), -1.0f), 1.0f);
    int a3 = (int)fminf(fmaxf(rintf(v.w / alpha), -1.0f), 1.0f);
    t4[i] = (a0 & 0xFF) | ((a1 & 0xFF) << 8) | ((a2 & 0xFF) << 16) | (a3 << 24);
  }
}

// ---------------- K3: per-row absmax + int8 quant of x ----------------
__global__ __launch_bounds__(256) void k_quant_x(const float* __restrict__ x,
                                                 int8_t* __restrict__ q,
                                                 float* __restrict__ gamma) {
  const int row = blockIdx.x;
  const float4* xr = (const float4*)(x + (size_t)row * FAN_IN);
  float4 v[4];
  float m = 0.0f;
#pragma unroll
  for (int i = 0; i < 4; ++i) {
    v[i] = xr[threadIdx.x + i * 256];
    m = fmaxf(m, fmaxf(fmaxf(fabsf(v[i].x), fabsf(v[i].y)),
                       fmaxf(fabsf(v[i].z), fabsf(v[i].w))));
  }
#pragma unroll
  for (int off = 32; off > 0; off >>= 1) m = fmaxf(m, __shfl_down(m, off));
  __shared__ float sm[4];
  if ((threadIdx.x & 63) == 0) sm[threadIdx.x >> 6] = m;
  __syncthreads();
  float g = fmaxf(fmaxf(sm[0], sm[1]), fmaxf(sm[2], sm[3]));
  g = fmaxf(g, 1e-8f);
  const float sc = 127.0f / g;
  int* qr = (int*)(q + (size_t)row * FAN_IN);
#pragma unroll
  for (int i = 0; i < 4; ++i) {
    int b0 = (int)rintf(v[i].x * sc);
    int b1 = (int)rintf(v[i].y * sc);
    int b2 = (int)rintf(v[i].z * sc);
    int b3 = (int)rintf(v[i].w * sc);
    qr[threadIdx.x + i * 256] =
        (b0 & 0xFF) | ((b1 & 0xFF) << 8) | ((b2 & 0xFF) << 16) | (b3 << 24);
  }
  if (threadIdx.x == 0) gamma[row] = g;
}

// ---------------- K4: int8 GEMM, 256x256 tile, BK=128, deep-prefetch --------
// Same skeleton as the verified bf16 8-phase kernel but i8/mfma_i32_16x16x64:
// per K-tile the byte-level LDS geometry is IDENTICAL (128 B rows, 8 x 16 B
// chunks, source-side swizzle cc^(m&7) -> measured 0 bank conflicts), but one
// tile now covers K=128, so KTILES halves (32) at unchanged per-tile cost.
// Prefetch map (deeper than before): during tile t
//   ph0: issue 4 A-loads of tile t+1 (dbuf fully free at tile start)
//   ph2: issue 2 B-loads of tile t+2 into cB (free after ph1-end barrier)
//   ph3: issue 2 B-loads of tile t+2; after MFMA: s_waitcnt vmcnt(4)
// -> tile t+1's 8 loads have 3-5 phases of latency cover; 4 loads remain in
// flight across every steady-state barrier (drain only at the tail).

#define BM 256
#define BN 256
#define BK 128                 // i8 elements; 128 B per row per tile
#define KTILES (FAN_IN / BK)   // 32

#define GLOAD(gp, lp) \
  __builtin_amdgcn_global_load_lds( \
      (const __attribute__((address_space(1))) uint32_t*)(gp), \
      (__attribute__((address_space(3))) uint32_t*)(lp), 16, 0, 0)

// raw barrier with compiler memory fence: no vmcnt drain, no mem-op motion across
#define BAR() asm volatile("s_barrier" ::: "memory")

__global__ __launch_bounds__(512, 2) void k_gemm(const int8_t* __restrict__ Q,
                                                 const int8_t* __restrict__ T,
                                                 const float* __restrict__ gamma,
                                                 const double* __restrict__ sum,
                                                 float* __restrict__ out) {
  __shared__ __align__(16) int8_t As[2][BM * BK];   // 2 x 32 KiB
  __shared__ __align__(16) int8_t Bs[2][BM * BK];   // 2 x 32 KiB

  // bijective XCD swizzle (2048 % 8 == 0): each XCD owns 8 contiguous jn
  // columns; im sweeps inside -> concurrent ~4x8 tile window per XCD L2.
  const int bid = blockIdx.x;
  const int loc = bid >> 3;                   // 0..255 (sequential per XCD)
  const int im  = loc >> 3;                   // 0..31
  const int jn  = (bid & 7) * 8 + (loc & 7);  // 0..63
  const size_t i0 = (size_t)im * BM;
  const size_t j0 = (size_t)jn * BN;

  const int tid  = threadIdx.x;
  const int lane = tid & 63;
  const int wave = tid >> 6;
  const int wm = wave >> 2;                   // 0..1 (M)
  const int wn = wave & 3;                    // 0..3 (N)
  const int ldsbase = (tid & ~63) * 16;       // bytes; HW adds lane*16

  i32x4 acc[8][4] = {};
  const int8_t* gA[4];
  const int8_t* gB[4];
  int aOff[4][2], bOff[4][2];

  // staging map: issue s covers chunks ci = s*512+tid; row m=ci>>3, slot cc=ci&7
  // holds global chunk cg = cc ^ (m&7)  (chunk = 16 B = 16 i8)
#pragma unroll
  for (int s = 0; s < 4; ++s) {
    int ci = s * 512 + tid;
    int m  = ci >> 3;
    int cg = (ci & 7) ^ (m & 7);
    gA[s] = Q + (i0 + m) * FAN_IN + cg * 16;
    gB[s] = T + (j0 + m) * FAN_IN + cg * 16;
  }
  // fragment read offsets (bytes): row*128 + (crow ^ (row&7))*16 ; rows 64.. = +8192
#pragma unroll
  for (int f = 0; f < 4; ++f) {
#pragma unroll
    for (int kk = 0; kk < 2; ++kk) {
      const int crow = kk * 4 + (lane >> 4);
      const int ma = wm * 128 + f * 16 + (lane & 15);
      const int mb = wn * 64  + f * 16 + (lane & 15);
      aOff[f][kk] = ma * BK + ((crow ^ (ma & 7)) * 16);
      bOff[f][kk] = mb * BK + ((crow ^ (mb & 7)) * 16);
    }
  }

  int8_t* As0 = &As[0][0]; int8_t* As1 = &As[1][0];
  int8_t* Bs0 = &Bs[0][0]; int8_t* Bs1 = &Bs[1][0];

  // ---- prologue: tile0 A+B into buf0; tile1 B into buf1 (tile1 A issues in
  // tile0 ph0 per the steady-state pattern)
#pragma unroll
  for (int s = 0; s < 4; ++s) { GLOAD(gA[s], As0 + s * 8192 + ldsbase); gA[s] += BK; }
#pragma unroll
  for (int s = 0; s < 4; ++s) { GLOAD(gB[s], Bs0 + s * 8192 + ldsbase); gB[s] += BK; }
#pragma unroll
  for (int s = 0; s < 4; ++s) { GLOAD(gB[s], Bs1 + s * 8192 + ldsbase); gB[s] += BK; }
  asm volatile("s_waitcnt vmcnt(4)" ::: "memory");   // tile0's 8 landed
  BAR();

  // one K-tile = 4 phases; cA/cB = compute buffers, sA/sB = prefetch buffers
  auto tile = [&](int t, int8_t* cA, int8_t* cB, int8_t* sA, int8_t* sB) {
    i32x4 aR[4][2], bR[4][2];
    const bool pfA = (t + 1 < KTILES);   // A of t+1 -> sA
    const bool pfB = (t + 2 < KTILES);   // B of t+2 -> cB (free after ph1)
    // -------- phase 0: LD A(lo) x8 + B(0-1) x4 | issue 4x A(t+1) ----------
#pragma unroll
    for (int mi = 0; mi < 4; ++mi)
#pragma unroll
      for (int kk = 0; kk < 2; ++kk)
        aR[mi][kk] = *(const i32x4*)(cA + aOff[mi][kk]);
#pragma unroll
    for (int ni = 0; ni < 2; ++ni)
#pragma unroll
      for (int kk = 0; kk < 2; ++kk)
        bR[ni][kk] = *(const i32x4*)(cB + bOff[ni][kk]);
    if (pfA) {
#pragma unroll
      for (int s = 0; s < 4; ++s) { GLOAD(gA[s], sA + s * 8192 + ldsbase); gA[s] += BK; }
    }
    BAR();
    __builtin_amdgcn_s_setprio(1);
#pragma unroll
    for (int kk = 0; kk < 2; ++kk)
#pragma unroll
      for (int mi = 0; mi < 4; ++mi)
#pragma unroll
        for (int ni = 0; ni < 2; ++ni)
          acc[mi][ni] = __builtin_amdgcn_mfma_i32_16x16x64_i8(
              aR[mi][kk], bR[ni][kk], acc[mi][ni], 0, 0, 0);
    __builtin_amdgcn_s_setprio(0);
    BAR();
    // -------- phase 1: LD B(2-3) x4 | no issues --------------------------
#pragma unroll
    for (int ni = 2; ni < 4; ++ni)
#pragma unroll
      for (int kk = 0; kk < 2; ++kk)
        bR[ni][kk] = *(const i32x4*)(cB + bOff[ni][kk]);
    BAR();
    __builtin_amdgcn_s_setprio(1);
#pragma unroll
    for (int kk = 0; kk < 2; ++kk)
#pragma unroll
      for (int mi = 0; mi < 4; ++mi)
#pragma unroll
        for (int ni = 2; ni < 4; ++ni)
          acc[mi][ni] = __builtin_amdgcn_mfma_i32_16x16x64_i8(
              aR[mi][kk], bR[ni][kk], acc[mi][ni], 0, 0, 0);
    __builtin_amdgcn_s_setprio(0);
    BAR();
    // -------- phase 2: LD A(hi) x8 | issue 2x B(t+2) into cB -------------
    // cB reads completed by all waves before the ph1-end barrier.
#pragma unroll
    for (int mi = 0; mi < 4; ++mi)
#pragma unroll
      for (int kk = 0; kk < 2; ++kk)
        aR[mi][kk] = *(const i32x4*)(cA + 8192 + aOff[mi][kk]);
    if (pfB) {
      GLOAD(gB[0], cB + 0 * 8192 + ldsbase); gB[0] += BK;
      GLOAD(gB[1], cB + 1 * 8192 + ldsbase); gB[1] += BK;
    }
    BAR();
    __builtin_amdgcn_s_setprio(1);
#pragma unroll
    for (int kk = 0; kk < 2; ++kk)
#pragma unroll
      for (int mi = 0; mi < 4; ++mi)
#pragma unroll
        for (int ni = 0; ni < 2; ++ni)
          acc[4 + mi][ni] = __builtin_amdgcn_mfma_i32_16x16x64_i8(
              aR[mi][kk], bR[ni][kk], acc[4 + mi][ni], 0, 0, 0);
    __builtin_amdgcn_s_setprio(0);
    BAR();
    // -------- phase 3: issue 2x B(t+2) | MFMA | counted vmcnt | BAR ------
    if (pfB) {
      GLOAD(gB[2], cB + 2 * 8192 + ldsbase); gB[2] += BK;
      GLOAD(gB[3], cB + 3 * 8192 + ldsbase); gB[3] += BK;
    }
    BAR();
    __builtin_amdgcn_s_setprio(1);
#pragma unroll
    for (int kk = 0; kk < 2; ++kk)
#pragma unroll
      for (int mi = 0; mi < 4; ++mi)
#pragma unroll
        for (int ni = 2; ni < 4; ++ni)
          acc[4 + mi][ni] = __builtin_amdgcn_mfma_i32_16x16x64_i8(
              aR[mi][kk], bR[ni][kk], acc[4 + mi][ni], 0, 0, 0);
    __builtin_amdgcn_s_setprio(0);
    // wait AFTER this phase's MFMA: t+1's 8 loads done, t+2's 4 B in flight
    if (t + 2 < KTILES) {
      asm volatile("s_waitcnt vmcnt(4)" ::: "memory");
    } else if (t + 1 < KTILES) {
      asm volatile("s_waitcnt vmcnt(0)" ::: "memory");
    }
    BAR();
  };

  for (int tt = 0; tt < KTILES; tt += 2) {
    tile(tt,     As0, Bs0, As1, Bs1);
    tile(tt + 1, As1, Bs1, As0, Bs0);
  }

  // epilogue: C/D layout col=lane&15, row=(lane>>4)*4+r (dtype-independent)
  const float alpha = (float)(*sum / (double)NW_ELEM + 1e-8);
  const int lr = lane >> 4;
  const int lc = lane & 15;
#pragma unroll
  for (int mi = 0; mi < 8; ++mi) {
    size_t gi = i0 + wm * 128 + mi * 16 + lr * 4;
#pragma unroll
    for (int r = 0; r < 4; ++r) {
      const float scl = gamma[gi + r] * alpha * (1.0f / 127.0f);
      float* orow = out + (gi + r) * (size_t)FAN_OUT;
#pragma unroll
      for (int ni = 0; ni < 4; ++ni) {
        size_t gj = j0 + wn * 64 + ni * 16 + lc;
        orow[gj] = (float)acc[mi][ni][r] * scl;
      }
    }
  }
}

// ---------------- launch ----------------
extern "C" void kernel_launch(void* const* d_in, const int* in_sizes, int n_in,
                              void* d_out, int out_size, void* d_ws, size_t ws_size,
                              hipStream_t stream) {
  const float* x = (const float*)d_in[0];
  const float* w = (const float*)d_in[1];
  float* out = (float*)d_out;
  char* ws = (char*)d_ws;

  // ws layout: [0,8) fp64 sum | [1024, 33792) gamma (8192 f32)
  //            [1 MiB, +32 MiB) q int8 | then t int8 (64 MiB). Total ~97 MiB.
  double* sum = (double*)ws;
  float* gamma = (float*)(ws + 1024);
  int8_t* q = (int8_t*)(ws + (1u << 20));
  int8_t* t = (int8_t*)(ws + (size_t)(1u << 20) + (size_t)NROWS * FAN_IN);

  hipMemsetAsync(sum, 0, sizeof(double), stream);
  k_abs_sum<<<1024, 256, 0, stream>>>(w, sum);
  k_quant_w<<<4096, 256, 0, stream>>>(w, t, sum);
  k_quant_x<<<NROWS, 256, 0, stream>>>(x, q, gamma);
  k_gemm<<<(NROWS / BM) * (FAN_OUT / BN), 512, 0, stream>>>(q, t, gamma, sum, out);
}